// Round 3
// baseline (212.031 us; speedup 1.0000x reference)
//
#include <hip/hip_runtime.h>
#include <cmath>

#define NN 2048

#define EPSF 0.1f
#define K2 14.426950408889634f   /* (1/eps) * log2(e) */
#define LN2F 0.6931471805599453f

// ws layout (floats)
#define U_OFF   0
#define V_OFF   2048
#define ERR_OFF 4096
#define DU_OFF  4112
#define CWS_OFF 6160

__device__ __forceinline__ float fexp2(float x) { return __builtin_amdgcn_exp2f(x); }
__device__ __forceinline__ float flog2(float x) { return __builtin_amdgcn_logf(x); }

// online logsumexp combine in base-2 domain: (M,S) <- (M,S) ++ (m,s)
__device__ __forceinline__ void lse_combine(float& M, float& S, float m, float s) {
    float mn = fmaxf(M, m);
    S = S * fexp2(M - mn) + s * fexp2(m - mn);
    M = mn;
}

__device__ __forceinline__ bool sink_done(const float* __restrict__ err, int it) {
    for (int k = 0; k < it; ++k)
        if (err[k] < 0.1f) return true;
    return false;
}

// ---------------------------------------------------------------------------
// Kernel 1: C[i][j] = sum_d (x[i][d]-y[j][d])^2 -> Cout (output) + Cws (aligned)
// Also zero-inits u/v/err/du and cost. grid (32, 16), block 256.
// ---------------------------------------------------------------------------
__global__ __launch_bounds__(256) void sink_cost_matrix(
        const float* __restrict__ x, const float* __restrict__ y,
        float* __restrict__ Cout, float* __restrict__ Cws,
        float* __restrict__ wsz, float* __restrict__ cost) {
    __shared__ float xs[128][65];
    __shared__ float ys[64][65];
    int tid = threadIdx.x;
    int bj = blockIdx.x, bi = blockIdx.y;

    if (bi == 0 && bj == 0) {
        // u(2048) + v(2048) + err(16) + du(2048)
        for (int k = tid; k < 2048 + 2048 + 16 + 2048; k += 256) wsz[k] = 0.f;
        if (tid == 0) cost[0] = 0.f;
    }

    const float4* x4 = (const float4*)x;
    const float4* y4 = (const float4*)y;
    for (int q = tid; q < 128 * 16; q += 256) {
        int r = q >> 4, dq = q & 15;
        float4 val = x4[(size_t)(bi * 128 + r) * 16 + dq];
        xs[r][dq * 4 + 0] = val.x; xs[r][dq * 4 + 1] = val.y;
        xs[r][dq * 4 + 2] = val.z; xs[r][dq * 4 + 3] = val.w;
    }
    for (int q = tid; q < 64 * 16; q += 256) {
        int r = q >> 4, dq = q & 15;
        float4 val = y4[(size_t)(bj * 64 + r) * 16 + dq];
        ys[r][dq * 4 + 0] = val.x; ys[r][dq * 4 + 1] = val.y;
        ys[r][dq * 4 + 2] = val.z; ys[r][dq * 4 + 3] = val.w;
    }
    __syncthreads();

    int tx = tid & 15, ty = tid >> 4;
    float acc[8][4];
#pragma unroll
    for (int ii = 0; ii < 8; ++ii)
#pragma unroll
        for (int jj = 0; jj < 4; ++jj) acc[ii][jj] = 0.f;

#pragma unroll 4
    for (int dd = 0; dd < 64; ++dd) {
        float xv[8], yv[4];
#pragma unroll
        for (int ii = 0; ii < 8; ++ii) xv[ii] = xs[ty + 16 * ii][dd];
#pragma unroll
        for (int jj = 0; jj < 4; ++jj) yv[jj] = ys[tx + 16 * jj][dd];
#pragma unroll
        for (int ii = 0; ii < 8; ++ii)
#pragma unroll
            for (int jj = 0; jj < 4; ++jj) {
                float d = xv[ii] - yv[jj];
                acc[ii][jj] = fmaf(d, d, acc[ii][jj]);
            }
    }

#pragma unroll
    for (int ii = 0; ii < 8; ++ii)
#pragma unroll
        for (int jj = 0; jj < 4; ++jj) {
            int gi = bi * 128 + ty + 16 * ii;
            int gj = bj * 64 + tx + 16 * jj;
            Cout[(size_t)gi * NN + gj] = acc[ii][jj];
            Cws [(size_t)gi * NN + gj] = acc[ii][jj];
        }
}

// ---------------------------------------------------------------------------
// Kernel 2 (per iter): u_i = eps*(log_mu - LSE_j((v_j - C_ij)/eps)); du_i=|Δ|
// grid 512, block 256: wave w handles row i = 4*blockIdx + w. No LDS.
// ---------------------------------------------------------------------------
__global__ __launch_bounds__(256) void sink_row(
        const float* __restrict__ Cws, float* __restrict__ u,
        const float* __restrict__ v, const float* __restrict__ err,
        float* __restrict__ du, int it, float log_mu) {
    if (sink_done(err, it)) return;
    int tid = threadIdx.x;
    int w = tid >> 6, l = tid & 63;
    int i = blockIdx.x * 4 + w;
    const float4* row4 = (const float4*)(Cws + (size_t)i * NN);
    const float4* v4 = (const float4*)v;

    float m0 = -INFINITY, m1 = -INFINITY, m2 = -INFINITY, m3 = -INFINITY;
    float s0 = 0.f, s1 = 0.f, s2 = 0.f, s3 = 0.f;
#pragma unroll
    for (int t = 0; t < 8; ++t) {
        int k = l + 64 * t;
        float4 c = row4[k];
        float4 vv = v4[k];
        lse_combine(m0, s0, (vv.x - c.x) * K2, 1.0f);
        lse_combine(m1, s1, (vv.y - c.y) * K2, 1.0f);
        lse_combine(m2, s2, (vv.z - c.z) * K2, 1.0f);
        lse_combine(m3, s3, (vv.w - c.w) * K2, 1.0f);
    }
    lse_combine(m0, s0, m1, s1);
    lse_combine(m2, s2, m3, s3);
    lse_combine(m0, s0, m2, s2);
#pragma unroll
    for (int off = 1; off < 64; off <<= 1) {
        float mo = __shfl_xor(m0, off);
        float so = __shfl_xor(s0, off);
        lse_combine(m0, s0, mo, so);
    }
    if (l == 0) {
        float un = EPSF * (log_mu - LN2F * (m0 + flog2(s0)));
        du[i] = fabsf(un - u[i]);
        u[i] = un;
    }
}

// ---------------------------------------------------------------------------
// Kernel 3 (per iter): v_j = eps*(log_nu - LSE_i((u_i - C_ij)/eps)).
// grid 256, block 256. Block owns 8 cols (j0=8b). Wave w covers rows
// [512w, 512w+512); lane: piece p=l&1 (float4 of 4 cols), row-within-step
// l>>1 (32 rows/step, 16 steps). Coalesced 32B-per-row reads.
// Block 0 additionally reduces du -> err[it].
// ---------------------------------------------------------------------------
__global__ __launch_bounds__(256) void sink_col(
        const float* __restrict__ Cws, const float* __restrict__ u,
        float* __restrict__ v, const float* __restrict__ du,
        float* __restrict__ err, int it, float log_nu) {
    if (sink_done(err, it)) return;
    int tid = threadIdx.x;
    int w = tid >> 6, l = tid & 63;
    int j0 = blockIdx.x * 8;
    int p = l & 1;            // which float4 (cols j0+4p .. j0+4p+3)
    int rl = l >> 1;          // row offset within step (0..31)

    float m0 = -INFINITY, m1 = -INFINITY, m2 = -INFINITY, m3 = -INFINITY;
    float s0 = 0.f, s1 = 0.f, s2 = 0.f, s3 = 0.f;
#pragma unroll 4
    for (int t = 0; t < 16; ++t) {
        int r = 512 * w + 32 * t + rl;
        float ur = u[r];
        float4 c = *(const float4*)(Cws + (size_t)r * NN + j0 + 4 * p);
        lse_combine(m0, s0, (ur - c.x) * K2, 1.0f);
        lse_combine(m1, s1, (ur - c.y) * K2, 1.0f);
        lse_combine(m2, s2, (ur - c.z) * K2, 1.0f);
        lse_combine(m3, s3, (ur - c.w) * K2, 1.0f);
    }
    // reduce across the 32 lanes sharing p (xor bits 1..5)
#pragma unroll
    for (int off = 2; off < 64; off <<= 1) {
        float t0, t1;
        t0 = __shfl_xor(m0, off); t1 = __shfl_xor(s0, off); lse_combine(m0, s0, t0, t1);
        t0 = __shfl_xor(m1, off); t1 = __shfl_xor(s1, off); lse_combine(m1, s1, t0, t1);
        t0 = __shfl_xor(m2, off); t1 = __shfl_xor(s2, off); lse_combine(m2, s2, t0, t1);
        t0 = __shfl_xor(m3, off); t1 = __shfl_xor(s3, off); lse_combine(m3, s3, t0, t1);
    }
    __shared__ float sm[4][8], ss[4][8];
    if (l < 2) {
        sm[w][4 * p + 0] = m0; ss[w][4 * p + 0] = s0;
        sm[w][4 * p + 1] = m1; ss[w][4 * p + 1] = s1;
        sm[w][4 * p + 2] = m2; ss[w][4 * p + 2] = s2;
        sm[w][4 * p + 3] = m3; ss[w][4 * p + 3] = s3;
    }
    __syncthreads();
    if (tid < 8) {
        float M = sm[0][tid], S = ss[0][tid];
#pragma unroll
        for (int q = 1; q < 4; ++q) lse_combine(M, S, sm[q][tid], ss[q][tid]);
        v[j0 + tid] = EPSF * (log_nu - LN2F * (M + flog2(S)));
    }

    if (blockIdx.x == 0) {
        // du -> err[it]
        float t = 0.f;
        for (int k = tid; k < NN; k += 256) t += du[k];
#pragma unroll
        for (int off = 1; off < 64; off <<= 1) t += __shfl_xor(t, off);
        __shared__ float sl[4];
        if ((tid & 63) == 0) sl[tid >> 6] = t;
        __syncthreads();
        if (tid == 0) err[it] = sl[0] + sl[1] + sl[2] + sl[3];
    }
}

// ---------------------------------------------------------------------------
// Kernel 4: pi = exp((-C+u+v)/eps), cost = sum(pi*C)
// grid 256 (8 rows per block), block 256. One atomic per block.
// ---------------------------------------------------------------------------
__global__ __launch_bounds__(256) void sink_pi(
        const float* __restrict__ Cws, const float* __restrict__ u,
        const float* __restrict__ v, float* __restrict__ pi,
        float* __restrict__ cost) {
    int tid = threadIdx.x;
    const float4* v4 = (const float4*)v;
    float local = 0.f;
    for (int rr = 0; rr < 8; ++rr) {
        int i = blockIdx.x * 8 + rr;
        float ui = u[i];
        const float4* row4 = (const float4*)(Cws + (size_t)i * NN);
        float* prow = pi + (size_t)i * NN;
        for (int k = tid; k < NN / 4; k += 256) {
            float4 c = row4[k];
            float4 vv = v4[k];
            float p0 = fexp2((ui + vv.x - c.x) * K2);
            float p1 = fexp2((ui + vv.y - c.y) * K2);
            float p2 = fexp2((ui + vv.z - c.z) * K2);
            float p3 = fexp2((ui + vv.w - c.w) * K2);
            prow[4 * k + 0] = p0;
            prow[4 * k + 1] = p1;
            prow[4 * k + 2] = p2;
            prow[4 * k + 3] = p3;
            local = fmaf(p0, c.x, local);
            local = fmaf(p1, c.y, local);
            local = fmaf(p2, c.z, local);
            local = fmaf(p3, c.w, local);
        }
    }
#pragma unroll
    for (int off = 1; off < 64; off <<= 1) local += __shfl_xor(local, off);
    __shared__ float sl[4];
    if ((tid & 63) == 0) sl[tid >> 6] = local;
    __syncthreads();
    if (tid == 0) atomicAdd(cost, sl[0] + sl[1] + sl[2] + sl[3]);
}

extern "C" void kernel_launch(void* const* d_in, const int* in_sizes, int n_in,
                              void* d_out, int out_size, void* d_ws, size_t ws_size,
                              hipStream_t stream) {
    const float* x = (const float*)d_in[0];
    const float* y = (const float*)d_in[1];
    float* out  = (float*)d_out;
    float* cost = out;                       // [0]
    float* pi   = out + 1;                   // [1 .. 1+2048*2048)
    float* Cout = out + 1 + (size_t)NN * NN; // [.. 1+2*2048*2048)

    float* ws  = (float*)d_ws;
    float* u   = ws + U_OFF;
    float* v   = ws + V_OFF;
    float* err = ws + ERR_OFF;
    float* du  = ws + DU_OFF;
    float* Cws = ws + CWS_OFF;

    float log_mu = (float)log(1.0 / 2048.0 + 1e-8); // n == m -> log_nu == log_mu

    sink_cost_matrix<<<dim3(32, 16), 256, 0, stream>>>(x, y, Cout, Cws, ws, cost);
    for (int it = 0; it < 10; ++it) {
        sink_row<<<512, 256, 0, stream>>>(Cws, u, v, err, du, it, log_mu);
        sink_col<<<256, 256, 0, stream>>>(Cws, u, v, du, err, it, log_mu);
    }
    sink_pi<<<256, 256, 0, stream>>>(Cws, u, v, pi, cost);
}

// Round 4
// 197.016 us; speedup vs baseline: 1.0762x; 1.0762x over previous
//
#include <hip/hip_runtime.h>
#include <cmath>

#define NN 2048

#define EPSF 0.1f
#define K2 14.426950408889634f   /* (1/eps) * log2(e) */
#define LN2F 0.6931471805599453f

// ws layout (floats)
#define U_OFF   0
#define V_OFF   2048
#define ERR_OFF 4096
#define FLG_OFF 4112
#define DU_OFF  4128
#define CWS_OFF 6176
#define PM_OFF  (6176 + 2048*2048)
#define PS_OFF  (PM_OFF + 256*2048)

__device__ __forceinline__ float fexp2(float x) { return __builtin_amdgcn_exp2f(x); }
__device__ __forceinline__ float flog2(float x) { return __builtin_amdgcn_logf(x); }

// online logsumexp combine in base-2 domain: (M,S) <- (M,S) ++ (m,s)
__device__ __forceinline__ void lse_combine(float& M, float& S, float m, float s) {
    float mn = fmaxf(M, m);
    S = S * fexp2(M - mn) + s * fexp2(m - mn);
    M = mn;
}

// ---------------------------------------------------------------------------
// Kernel 1: C[i][j] = sum_d (x[i][d]-y[j][d])^2 -> Cout (output) + Cws (aligned)
// Also zero-inits u/v/err/flag/du and cost. grid (32, 16), block 256.
// ---------------------------------------------------------------------------
__global__ __launch_bounds__(256) void sink_cost_matrix(
        const float* __restrict__ x, const float* __restrict__ y,
        float* __restrict__ Cout, float* __restrict__ Cws,
        float* __restrict__ wsz, float* __restrict__ cost) {
    __shared__ float xs[128][65];
    __shared__ float ys[64][65];
    int tid = threadIdx.x;
    int bj = blockIdx.x, bi = blockIdx.y;

    if (bi == 0 && bj == 0) {
        // u(2048)+v(2048)+err(16)+flag(16)+du(2048) = 6176
        for (int k = tid; k < 6176; k += 256) wsz[k] = 0.f;
        if (tid == 0) cost[0] = 0.f;
    }

    const float4* x4 = (const float4*)x;
    const float4* y4 = (const float4*)y;
    for (int q = tid; q < 128 * 16; q += 256) {
        int r = q >> 4, dq = q & 15;
        float4 val = x4[(size_t)(bi * 128 + r) * 16 + dq];
        xs[r][dq * 4 + 0] = val.x; xs[r][dq * 4 + 1] = val.y;
        xs[r][dq * 4 + 2] = val.z; xs[r][dq * 4 + 3] = val.w;
    }
    for (int q = tid; q < 64 * 16; q += 256) {
        int r = q >> 4, dq = q & 15;
        float4 val = y4[(size_t)(bj * 64 + r) * 16 + dq];
        ys[r][dq * 4 + 0] = val.x; ys[r][dq * 4 + 1] = val.y;
        ys[r][dq * 4 + 2] = val.z; ys[r][dq * 4 + 3] = val.w;
    }
    __syncthreads();

    int tx = tid & 15, ty = tid >> 4;
    float acc[8][4];
#pragma unroll
    for (int ii = 0; ii < 8; ++ii)
#pragma unroll
        for (int jj = 0; jj < 4; ++jj) acc[ii][jj] = 0.f;

#pragma unroll 4
    for (int dd = 0; dd < 64; ++dd) {
        float xv[8], yv[4];
#pragma unroll
        for (int ii = 0; ii < 8; ++ii) xv[ii] = xs[ty + 16 * ii][dd];
#pragma unroll
        for (int jj = 0; jj < 4; ++jj) yv[jj] = ys[tx + 16 * jj][dd];
#pragma unroll
        for (int ii = 0; ii < 8; ++ii)
#pragma unroll
            for (int jj = 0; jj < 4; ++jj) {
                float d = xv[ii] - yv[jj];
                acc[ii][jj] = fmaf(d, d, acc[ii][jj]);
            }
    }

#pragma unroll
    for (int ii = 0; ii < 8; ++ii)
#pragma unroll
        for (int jj = 0; jj < 4; ++jj) {
            int gi = bi * 128 + ty + 16 * ii;
            int gj = bj * 64 + tx + 16 * jj;
            Cout[(size_t)gi * NN + gj] = acc[ii][jj];
            Cws [(size_t)gi * NN + gj] = acc[ii][jj];
        }
}

// ---------------------------------------------------------------------------
// Kernel 2 (per iter): ONE pass over C.
// grid 256, block 256. Block b owns rows [8b, 8b+8).
// Thread t owns cols {4t..4t+3} and {1024+4t..1024+4t+3}.
// Phase 1 (row): u_i = eps*(log_mu - LSE_j((v_j - C_ij)/eps)), du_i = |Δu|.
// Phase 2 (col): per-block column partials (m,s) of (u_new_i - C_ij)/eps
//                over the 8 rows, written panel-major pm/ps[b*2048 + j].
// Gate: flag[it-1] || err[it-1] < 0.1 -> publish flag[it], skip.
// ---------------------------------------------------------------------------
__global__ __launch_bounds__(256) void sink_iter(
        const float* __restrict__ Cws, float* __restrict__ u,
        const float* __restrict__ v, float* __restrict__ du,
        const float* __restrict__ err, float* __restrict__ flag,
        float* __restrict__ pm, float* __restrict__ ps,
        int it, float log_mu) {
    int tid = threadIdx.x;
    if (it > 0) {
        if (flag[it - 1] != 0.f || err[it - 1] < 0.1f) {
            if (blockIdx.x == 0 && tid == 0) flag[it] = 1.f;
            return;
        }
    }
    int r0 = blockIdx.x * 8;
    int w = tid >> 6;

    // load v*K2 for my 8 cols
    float4 va = *(const float4*)(v + 4 * tid);
    float4 vb = *(const float4*)(v + 1024 + 4 * tid);
    float vK[8] = { va.x * K2, va.y * K2, va.z * K2, va.w * K2,
                    vb.x * K2, vb.y * K2, vb.z * K2, vb.w * K2 };

    // load C tile: 8 rows x 8 cols -> a[r][g] = (v_j - C_ij)*K2
    float a[8][8];
#pragma unroll
    for (int r = 0; r < 8; ++r) {
        const float* row = Cws + (size_t)(r0 + r) * NN;
        float4 ca = *(const float4*)(row + 4 * tid);
        float4 cb = *(const float4*)(row + 1024 + 4 * tid);
        a[r][0] = vK[0] - ca.x * K2; a[r][1] = vK[1] - ca.y * K2;
        a[r][2] = vK[2] - ca.z * K2; a[r][3] = vK[3] - ca.w * K2;
        a[r][4] = vK[4] - cb.x * K2; a[r][5] = vK[5] - cb.y * K2;
        a[r][6] = vK[6] - cb.z * K2; a[r][7] = vK[7] - cb.w * K2;
    }

    // ---- row phase: block-wide max per row ----
    float am[8];
#pragma unroll
    for (int r = 0; r < 8; ++r) {
        float m0 = fmaxf(fmaxf(a[r][0], a[r][1]), fmaxf(a[r][2], a[r][3]));
        float m1 = fmaxf(fmaxf(a[r][4], a[r][5]), fmaxf(a[r][6], a[r][7]));
        am[r] = fmaxf(m0, m1);
    }
#pragma unroll
    for (int off = 1; off < 64; off <<= 1)
#pragma unroll
        for (int r = 0; r < 8; ++r)
            am[r] = fmaxf(am[r], __shfl_xor(am[r], off));
    __shared__ float wsm[4][8];
    if ((tid & 63) == 0)
#pragma unroll
        for (int r = 0; r < 8; ++r) wsm[w][r] = am[r];
    __syncthreads();
    float M[8];
#pragma unroll
    for (int r = 0; r < 8; ++r)
        M[r] = fmaxf(fmaxf(wsm[0][r], wsm[1][r]), fmaxf(wsm[2][r], wsm[3][r]));

    // ---- row phase: sums with final max ----
    float s[8];
#pragma unroll
    for (int r = 0; r < 8; ++r) {
        float t0 = fexp2(a[r][0] - M[r]) + fexp2(a[r][1] - M[r]);
        float t1 = fexp2(a[r][2] - M[r]) + fexp2(a[r][3] - M[r]);
        float t2 = fexp2(a[r][4] - M[r]) + fexp2(a[r][5] - M[r]);
        float t3 = fexp2(a[r][6] - M[r]) + fexp2(a[r][7] - M[r]);
        s[r] = (t0 + t1) + (t2 + t3);
    }
#pragma unroll
    for (int off = 1; off < 64; off <<= 1)
#pragma unroll
        for (int r = 0; r < 8; ++r)
            s[r] += __shfl_xor(s[r], off);
    __shared__ float wss[4][8];
    if ((tid & 63) == 0)
#pragma unroll
        for (int r = 0; r < 8; ++r) wss[w][r] = s[r];
    __syncthreads();

    __shared__ float uK[8];
    if (tid < 8) {
        float S = (wss[0][tid] + wss[1][tid]) + (wss[2][tid] + wss[3][tid]);
        float un = EPSF * (log_mu - LN2F * (M[tid] + flog2(S)));
        du[r0 + tid] = fabsf(un - u[r0 + tid]);
        u[r0 + tid] = un;
        uK[tid] = un * K2;
        if (blockIdx.x == 0 && tid == 0 && it < 15) flag[it] = 0.f;
    }
    __syncthreads();

    // ---- col phase: b_rj = a[r][j] + (u_r - v_j)*K2, partial LSE over 8 rows
    float uKr[8];
#pragma unroll
    for (int r = 0; r < 8; ++r) uKr[r] = uK[r];

    float cm[8], cs[8];
#pragma unroll
    for (int g = 0; g < 8; ++g) {
        float b0 = a[0][g] + (uKr[0] - vK[g]);
        float b1 = a[1][g] + (uKr[1] - vK[g]);
        float b2 = a[2][g] + (uKr[2] - vK[g]);
        float b3 = a[3][g] + (uKr[3] - vK[g]);
        float b4 = a[4][g] + (uKr[4] - vK[g]);
        float b5 = a[5][g] + (uKr[5] - vK[g]);
        float b6 = a[6][g] + (uKr[6] - vK[g]);
        float b7 = a[7][g] + (uKr[7] - vK[g]);
        float m = fmaxf(fmaxf(fmaxf(b0, b1), fmaxf(b2, b3)),
                        fmaxf(fmaxf(b4, b5), fmaxf(b6, b7)));
        float t0 = fexp2(b0 - m) + fexp2(b1 - m);
        float t1 = fexp2(b2 - m) + fexp2(b3 - m);
        float t2 = fexp2(b4 - m) + fexp2(b5 - m);
        float t3 = fexp2(b6 - m) + fexp2(b7 - m);
        cm[g] = m;
        cs[g] = (t0 + t1) + (t2 + t3);
    }
    size_t base = (size_t)blockIdx.x * NN;
    *(float4*)(pm + base + 4 * tid)        = make_float4(cm[0], cm[1], cm[2], cm[3]);
    *(float4*)(pm + base + 1024 + 4 * tid) = make_float4(cm[4], cm[5], cm[6], cm[7]);
    *(float4*)(ps + base + 4 * tid)        = make_float4(cs[0], cs[1], cs[2], cs[3]);
    *(float4*)(ps + base + 1024 + 4 * tid) = make_float4(cs[4], cs[5], cs[6], cs[7]);
}

// ---------------------------------------------------------------------------
// Kernel 3 (per iter): finish column LSE -> v_j; block 0 reduces du -> err[it].
// grid 128, block 256: 16 cols/block, 16 threads/col, 16 panels each.
// ---------------------------------------------------------------------------
__global__ __launch_bounds__(256) void sink_fin(
        const float* __restrict__ pm, const float* __restrict__ ps,
        float* __restrict__ v, const float* __restrict__ du,
        float* __restrict__ err, const float* __restrict__ flag,
        int it, float log_nu) {
    if (flag[it] != 0.f) return;
    int tid = threadIdx.x;
    int c = tid >> 4, l = tid & 15;
    int j = blockIdx.x * 16 + c;

    float M0 = -INFINITY, S0 = 0.f, M1 = -INFINITY, S1 = 0.f;
#pragma unroll
    for (int k = 0; k < 8; ++k) {
        int p0 = l * 16 + 2 * k, p1 = p0 + 1;
        lse_combine(M0, S0, pm[(size_t)p0 * NN + j], ps[(size_t)p0 * NN + j]);
        lse_combine(M1, S1, pm[(size_t)p1 * NN + j], ps[(size_t)p1 * NN + j]);
    }
    lse_combine(M0, S0, M1, S1);
#pragma unroll
    for (int off = 1; off < 16; off <<= 1) {
        float mo = __shfl_xor(M0, off);
        float so = __shfl_xor(S0, off);
        lse_combine(M0, S0, mo, so);
    }
    if (l == 0) v[j] = EPSF * (log_nu - LN2F * (M0 + flog2(S0)));

    if (blockIdx.x == 0) {
        float t = 0.f;
        for (int k = tid; k < NN; k += 256) t += du[k];
#pragma unroll
        for (int off = 1; off < 64; off <<= 1) t += __shfl_xor(t, off);
        __shared__ float sl[4];
        if ((tid & 63) == 0) sl[tid >> 6] = t;
        __syncthreads();
        if (tid == 0) err[it] = sl[0] + sl[1] + sl[2] + sl[3];
    }
}

// ---------------------------------------------------------------------------
// Kernel 4: pi = exp((-C+u+v)/eps), cost = sum(pi*C)
// grid 256 (8 rows per block), block 256. One atomic per block.
// ---------------------------------------------------------------------------
__global__ __launch_bounds__(256) void sink_pi(
        const float* __restrict__ Cws, const float* __restrict__ u,
        const float* __restrict__ v, float* __restrict__ pi,
        float* __restrict__ cost) {
    int tid = threadIdx.x;
    const float4* v4 = (const float4*)v;
    float local = 0.f;
    for (int rr = 0; rr < 8; ++rr) {
        int i = blockIdx.x * 8 + rr;
        float ui = u[i];
        const float4* row4 = (const float4*)(Cws + (size_t)i * NN);
        float* prow = pi + (size_t)i * NN;
        for (int k = tid; k < NN / 4; k += 256) {
            float4 c = row4[k];
            float4 vv = v4[k];
            float p0 = fexp2((ui + vv.x - c.x) * K2);
            float p1 = fexp2((ui + vv.y - c.y) * K2);
            float p2 = fexp2((ui + vv.z - c.z) * K2);
            float p3 = fexp2((ui + vv.w - c.w) * K2);
            prow[4 * k + 0] = p0;
            prow[4 * k + 1] = p1;
            prow[4 * k + 2] = p2;
            prow[4 * k + 3] = p3;
            local = fmaf(p0, c.x, local);
            local = fmaf(p1, c.y, local);
            local = fmaf(p2, c.z, local);
            local = fmaf(p3, c.w, local);
        }
    }
#pragma unroll
    for (int off = 1; off < 64; off <<= 1) local += __shfl_xor(local, off);
    __shared__ float sl[4];
    if ((tid & 63) == 0) sl[tid >> 6] = local;
    __syncthreads();
    if (tid == 0) atomicAdd(cost, sl[0] + sl[1] + sl[2] + sl[3]);
}

extern "C" void kernel_launch(void* const* d_in, const int* in_sizes, int n_in,
                              void* d_out, int out_size, void* d_ws, size_t ws_size,
                              hipStream_t stream) {
    const float* x = (const float*)d_in[0];
    const float* y = (const float*)d_in[1];
    float* out  = (float*)d_out;
    float* cost = out;                       // [0]
    float* pi   = out + 1;                   // [1 .. 1+2048*2048)
    float* Cout = out + 1 + (size_t)NN * NN; // [.. 1+2*2048*2048)

    float* ws   = (float*)d_ws;
    float* u    = ws + U_OFF;
    float* v    = ws + V_OFF;
    float* err  = ws + ERR_OFF;
    float* flag = ws + FLG_OFF;
    float* du   = ws + DU_OFF;
    float* Cws  = ws + CWS_OFF;
    float* pm   = ws + PM_OFF;
    float* ps   = ws + PS_OFF;

    float log_mu = (float)log(1.0 / 2048.0 + 1e-8); // n == m -> log_nu == log_mu

    sink_cost_matrix<<<dim3(32, 16), 256, 0, stream>>>(x, y, Cout, Cws, ws, cost);
    for (int it = 0; it < 10; ++it) {
        sink_iter<<<256, 256, 0, stream>>>(Cws, u, v, du, err, flag, pm, ps, it, log_mu);
        sink_fin<<<128, 256, 0, stream>>>(pm, ps, v, du, err, flag, it, log_mu);
    }
    sink_pi<<<256, 256, 0, stream>>>(Cws, u, v, pi, cost);
}